// Round 5
// baseline (168.192 us; speedup 1.0000x reference)
//
#include <hip/hip_runtime.h>
#include <stdint.h>

// Q2Linear int8 path, 2 dispatches — R16: B-direct-to-registers, depth-4 pipeline.
//   prep: unchanged (quantize x -> i8; pack w int32 -> i8). ~17us, at BW floor.
//   q8_gemm: i8 MFMA 32x32x32, tile 64m x 128n, BK=128, 512 blocks (2/CU).
//     DIAGNOSIS (R12/R14/R15 nulls + cycle budget): LDS read port is the floor —
//     96 ds_read_b128 x 12cyc = 1540 cyc/slab/CU vs 512 cyc MFMA. B has zero
//     intra-block reuse and is L2-resident per XCD -> B leaves LDS (halves the
//     LDS term). R13 tried this with 1-deep prefetch + __syncthreads vmcnt(0)
//     drains and exposed L2 latency; R16 uses R14's verified machinery instead:
//       - B in 4 named register sets bv0..bv3 (period-4 phases, compile-time
//         indices, no copies), loaded 4 slabs ahead => ~3 phases latency cover.
//       - one raw s_barrier per slab + counted `s_waitcnt vmcnt(4|5)`: retires
//         the A-DMA (in-order vmcnt) while B loads stay in flight (T4).
//       - sched_barrier(0) pins A-DMA-before-B issue so vmcnt counts are exact.
//       - scales via one float4 per 4 slabs (cur/next named rotation).
//     LDS: A dbuf only, 16 KB/block. A-read dup 4x stays (1KB x 8/slab/wave).
// Fragment maps: A/B row = lane&31, k-chunk = lane>>5; C/D col = lane&31,
// row = (reg&3) + 8*(reg>>2) + 4*(lane>>5). B chunk kp holds k-bytes kp*32+hi*16
// (R13-verified pairing with av chunk (kp*2+hi)).
// Ledger: R8 -36%; R9 -2.7x; R10 -2x; R11=R7 143.0; R12 32x32+setprio 144.1
// (issue-rate null); R13 direct-B 1-deep 151.9 (drain-exposed); R14 3-buf
// counted-vmcnt 146.2 (ILP-depth null); R15 4 blk/CU 150.6 (TLP null, MfmaUtil
// flat 14% -> LDS-port-bound). Pre-commit: null/regress => revert + ROOFLINE.

#define MM 1024
#define NN 4096
#define KK 4096
#define BK 128

typedef __attribute__((ext_vector_type(4))) int intx4;
typedef __attribute__((ext_vector_type(16))) int intx16;
typedef __attribute__((ext_vector_type(4))) float floatx4;
typedef __attribute__((ext_vector_type(16))) float floatx16;

typedef const __attribute__((address_space(1))) void global_cvoid;
typedef const __attribute__((address_space(1))) intx4 g_intx4;
typedef const __attribute__((address_space(1))) floatx4 g_floatx4;
typedef __attribute__((address_space(3))) void lds_void;

// ---- prep: quantize x (blocks < MM) OR pack w -> i8 --------------------------
__global__ __launch_bounds__(256) void prep(const float* __restrict__ x,
                                            const int* __restrict__ wq,
                                            char* __restrict__ xq,
                                            float* __restrict__ qrow,
                                            char* __restrict__ wb) {
    const int tid = threadIdx.x;
    if (blockIdx.x < MM) {
        const int m = blockIdx.x;
        const float* xr = x + (size_t)m * KK;
        floatx4 v[4];
        float amax = 0.f;
#pragma unroll
        for (int c = 0; c < 4; ++c) {
            v[c] = *(const floatx4*)(xr + (c * 256 + tid) * 4);
#pragma unroll
            for (int e = 0; e < 4; ++e) amax = fmaxf(amax, fabsf(v[c][e]));
        }
#pragma unroll
        for (int off = 32; off; off >>= 1) amax = fmaxf(amax, __shfl_down(amax, off));
        __shared__ float wmax[4];
        if ((tid & 63) == 0) wmax[tid >> 6] = amax;
        __syncthreads();
        amax = fmaxf(fmaxf(wmax[0], wmax[1]), fmaxf(wmax[2], wmax[3]));
        amax = fmaxf(amax, 1e-20f);
        const float qinv = 127.0f / amax;
        if (tid == 0) qrow[m] = amax / 127.0f;
#pragma unroll
        for (int c = 0; c < 4; ++c) {
            int p = 0;
#pragma unroll
            for (int e = 0; e < 4; ++e) {
                float r = rintf(v[c][e] * qinv);
                r = fminf(fmaxf(r, -127.f), 127.f);
                p |= ((int)r & 255) << (8 * e);
            }
            *(int*)(xq + (size_t)m * KK + (c * 256 + tid) * 4) = p;
        }
    } else {
        // pack w: fully coalesced (lane-consecutive 16B reads / 4B writes)
        const int blk = blockIdx.x - MM;
#pragma unroll
        for (int c = 0; c < 4; ++c) {
            size_t c4 = (size_t)blk * 1024 + c * 256 + tid;  // intx4-chunk id
            intx4 a = ((const intx4*)wq)[c4];
            ((int*)wb)[c4] = (a[0] & 255) | ((a[1] & 255) << 8) |
                             ((a[2] & 255) << 16) | (a[3] << 24);
        }
    }
}

// ---- GEMM: 64x128 tile, 4 waves (each 64m x 32n), A dbuf LDS, B in regs ------
__global__ __launch_bounds__(256, 2) void q8_gemm(const char* __restrict__ xq,
                                                  const char* __restrict__ wb,
                                                  const float* __restrict__ qrow,
                                                  const float* __restrict__ scales,
                                                  float* __restrict__ out) {
    __shared__ char As[2][64 * BK];    // 8 KB each -> 16 KB total

    const int tid  = threadIdx.x;
    const int lane = tid & 63;
    const int wave = tid >> 6;
    const int l31  = lane & 31;        // A/B fragment row, C/D col (n)
    const int hi   = lane >> 5;        // k-chunk half selector
    const int sw   = lane & 7;         // XOR-swizzle key (== row&7, A reads)
    const int wn   = wave * 32;        // wave's n offset within tile

    // XCD pinning: bid&7 -> XCD; each XCD owns 4 n-tiles (512 cols, 2MB B-strip)
    const int bid = blockIdx.x;
    const int xcd = bid & 7, loc = bid >> 3;   // loc 0..63
    const int nT = xcd * 4 + (loc & 3);        // 0..31
    const int mT = loc >> 2;                   // 0..15
    const int mBase = mT * 64, nBase = nT * 128;

    // A staging address permute -> XOR-swizzled LDS tile (R7-verified geometry)
    const int rg = lane >> 3;
    const int cs = (lane & 7) ^ rg;
    const char* gA = xq + (size_t)(mBase + wave * 16 + rg) * KK + cs * 16;
    const int ldsRow = wave * 16;

    // B: this lane's private row stream (L2-resident; chunk kp = k-bytes kp*32+hi*16)
    const char* gBrow = wb + (size_t)(nBase + wn + l31) * KK + hi * 16;
    // scales row for this lane's n-column
    const float* scrow = scales + (size_t)(nBase + wn + l31) * 32;

    floatx16 fac0, fac1;
#pragma unroll
    for (int r = 0; r < 16; ++r) { fac0[r] = 0.f; fac1[r] = 0.f; }

#define STAGE_A(BUF, SLAB)                                                      \
    {                                                                           \
        _Pragma("unroll")                                                       \
        for (int t = 0; t < 2; ++t)                                             \
            __builtin_amdgcn_global_load_lds(                                   \
                (global_cvoid*)(gA + (size_t)(t * 8) * KK + (size_t)(SLAB) * BK),\
                (lds_void*)&As[BUF][(ldsRow + t * 8) * BK], 16, 0, 0);          \
    }

#define LOAD_B(BV, SLAB)                                                        \
    {                                                                           \
        _Pragma("unroll")                                                       \
        for (int q = 0; q < 4; ++q)                                             \
            BV[q] = *(g_intx4*)(gBrow + (size_t)(SLAB) * BK + q * 32);          \
    }

    // per kp: av rows l31 / 32+l31 from swizzled LDS (8 ds_read_b128/slab/wave),
    // bv from registers. 8 MFMA + 64 fold VALU per slab per wave.
#define COMPUTE(BUF, BV, SF)                                                    \
    {                                                                           \
        intx16 iacc0, iacc1;                                                    \
        __builtin_amdgcn_s_setprio(1);                                          \
        _Pragma("unroll")                                                       \
        for (int kp = 0; kp < 4; ++kp) {                                        \
            const int kc = (((kp * 2) + hi) ^ sw) << 4;                         \
            intx4 av0 = *(const intx4*)&As[BUF][l31 * BK + kc];                 \
            intx4 av1 = *(const intx4*)&As[BUF][(32 + l31) * BK + kc];          \
            if (kp == 0) {                                                      \
                intx16 z = {0, 0, 0, 0, 0, 0, 0, 0, 0, 0, 0, 0, 0, 0, 0, 0};    \
                iacc0 = __builtin_amdgcn_mfma_i32_32x32x32_i8(av0, BV[0], z, 0, 0, 0); \
                iacc1 = __builtin_amdgcn_mfma_i32_32x32x32_i8(av1, BV[0], z, 0, 0, 0); \
            } else {                                                            \
                iacc0 = __builtin_amdgcn_mfma_i32_32x32x32_i8(av0, BV[kp], iacc0, 0, 0, 0); \
                iacc1 = __builtin_amdgcn_mfma_i32_32x32x32_i8(av1, BV[kp], iacc1, 0, 0, 0); \
            }                                                                   \
        }                                                                       \
        __builtin_amdgcn_s_setprio(0);                                          \
        _Pragma("unroll")                                                       \
        for (int r = 0; r < 16; ++r) {                                          \
            fac0[r] += (float)iacc0[r] * (SF);                                  \
            fac1[r] += (float)iacc1[r] * (SF);                                  \
        }                                                                       \
    }

    // Phase (slab s = base+PH): stage A(s+1) -> buf (PH+1)&1; compute buf PH&1
    // with B set PH; then load B(s+4) into set PH (SSA: old set consumed first).
    // vmcnt at barrier retires A(s+1): ops issued after it = 4 B (+1 sc at PH3).
#define PHASE(PH, BASE, BV, SF, WAITN)                                          \
    {                                                                           \
        STAGE_A((PH + 1) & 1, ((BASE) + (PH) + 1) & 31)                         \
        __builtin_amdgcn_sched_barrier(0);                                      \
        COMPUTE((PH) & 1, BV, SF)                                               \
        LOAD_B(BV, ((BASE) + (PH) + 4) & 31)                                    \
        asm volatile("s_waitcnt vmcnt(" #WAITN ")" ::: "memory");               \
        __builtin_amdgcn_s_barrier();                                           \
    }

    // prologue: A(0) DMA, B(0..3) into sets, scale groups 0 and 1
    intx4 bv0[4], bv1[4], bv2[4], bv3[4];
    STAGE_A(0, 0)
    __builtin_amdgcn_sched_barrier(0);
    LOAD_B(bv0, 0) LOAD_B(bv1, 1) LOAD_B(bv2, 2) LOAD_B(bv3, 3)
    floatx4 scv_c = *(g_floatx4*)(scrow + 0);
    floatx4 scv_n = *(g_floatx4*)(scrow + 4);
    // retire A(0): 18 vm ops issued after it (16 B + 2 scale)
    asm volatile("s_waitcnt vmcnt(18)" ::: "memory");
    __builtin_amdgcn_s_barrier();

    for (int base = 0; base < 32; base += 4) {
        PHASE(0, base, bv0, scv_c[0], 4)
        PHASE(1, base, bv1, scv_c[1], 4)
        PHASE(2, base, bv2, scv_c[2], 4)
        // PH3: also rotate scale groups (load next-next, 1 extra vm op -> vmcnt 5)
        {
            STAGE_A(0, (base + 4) & 31)
            __builtin_amdgcn_sched_barrier(0);
            COMPUTE(1, bv3, scv_c[3])
            LOAD_B(bv3, (base + 7) & 31)
            scv_c = scv_n;
            scv_n = *(g_floatx4*)(scrow + (((base >> 2) + 2) & 7) * 4);
            asm volatile("s_waitcnt vmcnt(5)" ::: "memory");
            __builtin_amdgcn_s_barrier();
        }
    }

    // epilogue: C/D col = lane&31 (n), row = (reg&3)+8*(reg>>2)+4*hi (m); fold q[m]
#pragma unroll
    for (int g = 0; g < 4; ++g) {
        floatx4 qv0 = *(const floatx4*)(qrow + mBase + g * 8 + hi * 4);
        floatx4 qv1 = *(const floatx4*)(qrow + mBase + 32 + g * 8 + hi * 4);
#pragma unroll
        for (int r = 0; r < 4; ++r) {
            const int m0 = mBase + g * 8 + hi * 4 + r;
            out[(size_t)m0 * NN + nBase + wn + l31]        = fac0[g * 4 + r] * qv0[r];
            out[(size_t)(m0 + 32) * NN + nBase + wn + l31] = fac1[g * 4 + r] * qv1[r];
        }
    }
#undef STAGE_A
#undef LOAD_B
#undef COMPUTE
#undef PHASE
}

extern "C" void kernel_launch(void* const* d_in, const int* in_sizes, int n_in,
                              void* d_out, int out_size, void* d_ws, size_t ws_size,
                              hipStream_t stream) {
    const float* x      = (const float*)d_in[0];
    const int*   wq     = (const int*)d_in[1];
    const float* scales = (const float*)d_in[2];
    float*       out    = (float*)d_out;

    char*  xq   = (char*)d_ws;                                   // 4 MB
    float* qrow = (float*)((char*)d_ws + (size_t)MM * KK);       // 4 KB
    char*  wb   = (char*)d_ws + (size_t)MM * KK + 4096;          // 16.8 MB

    prep<<<MM + (size_t)NN * KK / 16 / 256, 256, 0, stream>>>(x, wq, xq, qrow, wb);
    q8_gemm<<<(MM / 64) * (NN / 128), 256, 0, stream>>>(xq, wb, qrow, scales, out);
}

// Round 6
// 142.086 us; speedup vs baseline: 1.1837x; 1.1837x over previous
//
#include <hip/hip_runtime.h>
#include <stdint.h>

// Q2Linear int8 path, 2 dispatches — R17 = R11/R7 exact restore (best verified:
// 143.0 us). Per pre-commitment after the R12–R16 ablation ladder:
//   R12 MFMA-rate/setprio null; R13 direct-B 1-deep -8us; R14 counted-vmcnt
//   3-buf null; R15 4blk/CU TLP null (MfmaUtil flat 14%); R16 B->regs depth-4
//   VGPR-spill regress (128-cap hit, WRITE_SIZE 16KB->29MB scratch).
// Conclusion: the 2-barrier K-loop at this problem shape (M=1024 -> 512 tiles)
// sits at the sum of partially-overlapped floors (LDS port ~10us + L2/DMA ~11us
// + MFMA ~8us + fold ~4us ~= 41us gemm); timed region also carries ~83us of
// harness poison fills at HBM ceiling + prep ~17us at BW floor. Roofline.
//   prep: blocks 0..1023    — per-row quantize x fp32 -> i8 (q = rowmax/127)
//         blocks 1024..5119 — pack w int32 {-2..1} -> i8 (exact, coalesced)
//   q8_gemm: i8 MFMA 16x16x64, tile 64m x 128n, BK=128 (= one scale block),
//            512 blocks = 2/CU (LDS 64.9 KB). Both A and B staged via
//            global_load_lds(16B) into XOR-swizzled dbuf LDS (0 conflicts).
//            Scales staged once into padded LDS [n][33] so the K-loop has no
//            global loads besides the DMA (keeps the vmcnt prefetch queue clean).

#define MM 1024
#define NN 4096
#define KK 4096
#define BK 128

typedef __attribute__((ext_vector_type(4))) int intx4;
typedef __attribute__((ext_vector_type(4))) float floatx4;

typedef const __attribute__((address_space(1))) void global_cvoid;
typedef __attribute__((address_space(3))) void lds_void;

// ---- prep: quantize x (blocks < MM) OR pack w -> i8 --------------------------
__global__ __launch_bounds__(256) void prep(const float* __restrict__ x,
                                            const int* __restrict__ wq,
                                            char* __restrict__ xq,
                                            float* __restrict__ qrow,
                                            char* __restrict__ wb) {
    const int tid = threadIdx.x;
    if (blockIdx.x < MM) {
        const int m = blockIdx.x;
        const float* xr = x + (size_t)m * KK;
        floatx4 v[4];
        float amax = 0.f;
#pragma unroll
        for (int c = 0; c < 4; ++c) {
            v[c] = *(const floatx4*)(xr + (c * 256 + tid) * 4);
#pragma unroll
            for (int e = 0; e < 4; ++e) amax = fmaxf(amax, fabsf(v[c][e]));
        }
#pragma unroll
        for (int off = 32; off; off >>= 1) amax = fmaxf(amax, __shfl_down(amax, off));
        __shared__ float wmax[4];
        if ((tid & 63) == 0) wmax[tid >> 6] = amax;
        __syncthreads();
        amax = fmaxf(fmaxf(wmax[0], wmax[1]), fmaxf(wmax[2], wmax[3]));
        amax = fmaxf(amax, 1e-20f);
        const float qinv = 127.0f / amax;
        if (tid == 0) qrow[m] = amax / 127.0f;
#pragma unroll
        for (int c = 0; c < 4; ++c) {
            int p = 0;
#pragma unroll
            for (int e = 0; e < 4; ++e) {
                float r = rintf(v[c][e] * qinv);
                r = fminf(fmaxf(r, -127.f), 127.f);
                p |= ((int)r & 255) << (8 * e);
            }
            *(int*)(xq + (size_t)m * KK + (c * 256 + tid) * 4) = p;
        }
    } else {
        // pack w: fully coalesced (lane-consecutive 16B reads / 4B writes)
        const int blk = blockIdx.x - MM;
#pragma unroll
        for (int c = 0; c < 4; ++c) {
            size_t c4 = (size_t)blk * 1024 + c * 256 + tid;  // intx4-chunk id
            intx4 a = ((const intx4*)wq)[c4];
            ((int*)wb)[c4] = (a[0] & 255) | ((a[1] & 255) << 8) |
                             ((a[2] & 255) << 16) | (a[3] << 24);
        }
    }
}

// ---- GEMM: 64x128 tile, 4 waves (each 64m x 32n), double-buffered LDS --------
__global__ __launch_bounds__(256, 2) void q8_gemm(const char* __restrict__ xq,
                                                  const char* __restrict__ wb,
                                                  const float* __restrict__ qrow,
                                                  const float* __restrict__ scales,
                                                  float* __restrict__ out) {
    __shared__ char As[2][64 * BK];    // 8 KB each
    __shared__ char Bs[2][128 * BK];   // 16 KB each
    __shared__ float Sl[128 * 33];     // scales [n_local][block], +1 pad (16.9 KB)
    // total 64.9 KB -> 2 blocks/CU

    const int tid  = threadIdx.x;
    const int lane = tid & 63;
    const int wave = tid >> 6;
    const int r16  = lane & 15;
    const int quad = lane >> 4;
    const int sw   = r16 & 7;
    const int wn   = wave * 32;        // wave's n offset within tile

    // XCD pinning: bid&7 -> XCD; each XCD owns 4 n-tiles (512 cols, 2MB i8 B-strip)
    const int bid = blockIdx.x;
    const int xcd = bid & 7, loc = bid >> 3;   // loc 0..63
    const int nT = xcd * 4 + (loc & 3);        // 0..31
    const int mT = loc >> 2;                   // 0..15
    const int mBase = mT * 64, nBase = nT * 128;

    // staging address permute -> XOR-swizzled LDS tile (verified, 0 conflicts)
    const int rg = lane >> 3;
    const int cs = (lane & 7) ^ rg;
    const char* gA = xq + (size_t)(mBase + wave * 16 + rg) * KK + cs * 16;
    const char* gB = wb + (size_t)(nBase + wave * 32 + rg) * KK + cs * 16;
    const int ldsRowA = wave * 16;
    const int ldsRowB = wave * 32;

    floatx4 facc[4][2];
#pragma unroll
    for (int i = 0; i < 4; ++i)
#pragma unroll
        for (int j = 0; j < 2; ++j) facc[i][j] = (floatx4){0.f, 0.f, 0.f, 0.f};

#define STAGE(BUF, SLAB)                                                        \
    {                                                                           \
        _Pragma("unroll")                                                       \
        for (int t = 0; t < 2; ++t)                                             \
            __builtin_amdgcn_global_load_lds(                                   \
                (global_cvoid*)(gA + (size_t)(t * 8) * KK + (SLAB) * BK),       \
                (lds_void*)&As[BUF][(ldsRowA + t * 8) * BK], 16, 0, 0);         \
        _Pragma("unroll")                                                       \
        for (int t = 0; t < 4; ++t)                                             \
            __builtin_amdgcn_global_load_lds(                                   \
                (global_cvoid*)(gB + (size_t)(t * 8) * KK + (SLAB) * BK),       \
                (lds_void*)&Bs[BUF][(ldsRowB + t * 8) * BK], 16, 0, 0);         \
    }

#define COMPUTE(BUF, SLAB)                                                      \
    {                                                                           \
        float sf0 = Sl[(wn + r16) * 33 + (SLAB)];                               \
        float sf1 = Sl[(wn + 16 + r16) * 33 + (SLAB)];                          \
        intx4 iacc[4][2];                                                       \
        _Pragma("unroll")                                                       \
        for (int kp = 0; kp < 2; ++kp) {                                        \
            intx4 av[4], bv[2];                                                 \
            _Pragma("unroll")                                                   \
            for (int i = 0; i < 4; ++i)                                         \
                av[i] = *(const intx4*)&As[BUF][(i * 16 + r16) * BK +           \
                                               (((kp * 4 + quad) ^ sw) << 4)];  \
            _Pragma("unroll")                                                   \
            for (int j = 0; j < 2; ++j)                                         \
                bv[j] = *(const intx4*)&Bs[BUF][(wn + j * 16 + r16) * BK +      \
                                               (((kp * 4 + quad) ^ sw) << 4)];  \
            _Pragma("unroll")                                                   \
            for (int i = 0; i < 4; ++i)                                         \
                _Pragma("unroll")                                               \
                for (int j = 0; j < 2; ++j)                                     \
                    iacc[i][j] = __builtin_amdgcn_mfma_i32_16x16x64_i8(         \
                        av[i], bv[j], kp ? iacc[i][j] : (intx4){0, 0, 0, 0},    \
                        0, 0, 0);                                               \
        }                                                                       \
        _Pragma("unroll")                                                       \
        for (int i = 0; i < 4; ++i)                                             \
            _Pragma("unroll")                                                   \
            for (int r = 0; r < 4; ++r) {                                       \
                facc[i][0][r] += (float)iacc[i][0][r] * sf0;                    \
                facc[i][1][r] += (float)iacc[i][1][r] * sf1;                    \
            }                                                                   \
    }

    STAGE(0, 0)
    // stage scales once: coalesced global read; LDS banks (nl+b)%32 -> 2-way = free
    for (int t = tid; t < 4096; t += 256) {
        int nl = t >> 5, b = t & 31;
        Sl[nl * 33 + b] = scales[(size_t)(nBase + nl) * 32 + b];
    }
    __syncthreads();

    const int NIT = KK / BK;  // 32
    for (int it = 0; it < NIT; it += 2) {
        if (it + 1 < NIT) STAGE(1, it + 1)
        COMPUTE(0, it)
        __syncthreads();
        if (it + 2 < NIT) STAGE(0, it + 2)
        COMPUTE(1, it + 1)
        __syncthreads();
    }

    // epilogue: C/D col = lane&15 (n), row = quad*4 + reg (m); fold q[m]
#pragma unroll
    for (int i = 0; i < 4; ++i) {
        floatx4 qv = *(const floatx4*)(qrow + mBase + i * 16 + quad * 4);
#pragma unroll
        for (int r = 0; r < 4; ++r) {
            int mg = mBase + i * 16 + quad * 4 + r;
            float* orow = out + (size_t)mg * NN + nBase + wn + r16;
#pragma unroll
            for (int j = 0; j < 2; ++j) orow[j * 16] = facc[i][j][r] * qv[r];
        }
    }
#undef STAGE
#undef COMPUTE
}

extern "C" void kernel_launch(void* const* d_in, const int* in_sizes, int n_in,
                              void* d_out, int out_size, void* d_ws, size_t ws_size,
                              hipStream_t stream) {
    const float* x      = (const float*)d_in[0];
    const int*   wq     = (const int*)d_in[1];
    const float* scales = (const float*)d_in[2];
    float*       out    = (float*)d_out;

    char*  xq   = (char*)d_ws;                                   // 4 MB
    float* qrow = (float*)((char*)d_ws + (size_t)MM * KK);       // 4 KB
    char*  wb   = (char*)d_ws + (size_t)MM * KK + 4096;          // 16.8 MB

    prep<<<MM + (size_t)NN * KK / 16 / 256, 256, 0, stream>>>(x, wq, xq, qrow, wb);
    q8_gemm<<<(MM / 64) * (NN / 128), 256, 0, stream>>>(xq, wb, qrow, scales, out);
}